// Round 20
// baseline (559.903 us; speedup 1.0000x reference)
//
#include <hip/hip_runtime.h>
#include <hip/hip_bf16.h>

// Problem: B=64, N=577, E=1024, H=16, D=64.
// out = softmax((xWq^T)(xWk^T)^T / 8) (xWv^T), head-split.
// Buffers:
//   d_out doubles as scratch: xb bf16 [0,75628544) + Vb bf16 [75628544,151257088).
//   ws: Qb [0,SZ) + Kb [SZ,2SZ) + Vt [2SZ,2SZ+VTSZ) + Wb (6.3MB).
//   Vt = [bh][d][584] (16B-aligned rows).
// Wq is pre-scaled by 0.125*log2(e) -> scores arrive in the exp2 domain.

typedef __attribute__((ext_vector_type(8))) short s16x8;
typedef __attribute__((ext_vector_type(4))) float f32x4;
typedef __attribute__((ext_vector_type(16))) float f32x16;
typedef __attribute__((ext_vector_type(4))) unsigned int u32x4;
typedef __attribute__((ext_vector_type(2))) unsigned int u32x2;

#define MFMA16(a, b, c) __builtin_amdgcn_mfma_f32_16x16x32_bf16((a), (b), (c), 0, 0, 0)
#define MFMA32(a, b, c) __builtin_amdgcn_mfma_f32_32x32x16_bf16((a), (b), (c), 0, 0, 0)

__device__ __forceinline__ short f2bf(float f) {
    unsigned u = __builtin_bit_cast(unsigned, f);
    u += 0x7FFFu + ((u >> 16) & 1u);   // round-to-nearest-even
    return (short)(u >> 16);
}

__device__ __forceinline__ unsigned cvtpk(float lo, float hi) {
    unsigned r;
    asm("v_cvt_pk_bf16_f32 %0, %1, %2" : "=v"(r) : "v"(lo), "v"(hi));
    return r;
}

__device__ __forceinline__ void gload_lds16(const void* g, void* l) {
    __builtin_amdgcn_global_load_lds(
        (const __attribute__((address_space(1))) unsigned int*)g,
        (__attribute__((address_space(3))) unsigned int*)l,
        16, 0, 0);
}

// ---------------------------------------------------------------------------
// Convert x -> xb (d_out lo) and Wq|Wk|Wv -> Wb (ws) as bf16.
// Wq (wsel==0) is scaled by 0.125*log2(e).
// ---------------------------------------------------------------------------
__global__ __launch_bounds__(256) void convert_bf16(
    const float* __restrict__ x,
    const float* __restrict__ Wq,
    const float* __restrict__ Wk,
    const float* __restrict__ Wv,
    short* __restrict__ xb,
    short* __restrict__ Wb)
{
    constexpr size_t NX = 37814272u / 8u;
    constexpr size_t NW = 1048576u / 8u;
    constexpr size_t NTOT = NX + 3u * NW;
    size_t stride = (size_t)gridDim.x * blockDim.x;
    for (size_t c = (size_t)blockIdx.x * blockDim.x + threadIdx.x; c < NTOT; c += stride) {
        const float* src;
        short* dst;
        size_t off;
        float scale = 1.0f;
        if (c < NX) { src = x; off = c * 8; dst = xb + off; }
        else {
            size_t cw = c - NX;
            int wsel = (int)(cw / NW);
            src = (wsel == 0) ? Wq : (wsel == 1) ? Wk : Wv;
            if (wsel == 0) scale = 0.18033688011112042f;
            off = (cw - (size_t)wsel * NW) * 8;
            dst = Wb + cw * 8;
        }
        float4 a0 = *reinterpret_cast<const float4*>(src + off);
        float4 a1 = *reinterpret_cast<const float4*>(src + off + 4);
        s16x8 v;
        v[0]=f2bf(a0.x*scale); v[1]=f2bf(a0.y*scale); v[2]=f2bf(a0.z*scale); v[3]=f2bf(a0.w*scale);
        v[4]=f2bf(a1.x*scale); v[5]=f2bf(a1.y*scale); v[6]=f2bf(a1.z*scale); v[7]=f2bf(a1.w*scale);
        *reinterpret_cast<s16x8*>(dst) = v;
    }
}

// ---------------------------------------------------------------------------
// QKV GEMM v8: 128x128 tile, BK=64, 4 waves, 64 KiB LDS -> TWO blocks/CU.
// Same R10 ledger: quarters {Aks0,Bks0,Aks1,Bks1} of 2 loads/thread,
// CP1/CP2 vmcnt(4) + barrier, stages interleaved between phases, XOR swizzle.
// With 2 independent blocks per CU, one block's MFMA covers the other's
// barrier/vmcnt drain (m114 cross-wave-group overlap).
// ---------------------------------------------------------------------------
__global__ __launch_bounds__(256, 2) void qkv_gemm8(
    const short* __restrict__ xb,
    const short* __restrict__ Wb,
    short* __restrict__ Qb,
    short* __restrict__ Kb,
    short* __restrict__ Vb)
{
    constexpr int M = 36928;
    constexpr int NT = 24;                 // 3072/128
    constexpr int NWG = 289 * NT;          // 6936 (div by 8)
    __shared__ char LDS[65536];

    const int t    = threadIdx.x;
    const int lane = t & 63;
    const int w    = t >> 6;
    const int wr   = w >> 1, wc = w & 1;
    const int ml   = lane & 15, zz = lane >> 4;

    int bid = blockIdx.x;
    int id  = (bid & 7) * (NWG / 8) + (bid >> 3);
    const int tileM = (id / NT) * 128;
    const int tileN = (id % NT) * 128;

    const char* Ab = (const char*)xb;
    const char* Bb = (const char*)Wb;

    int s_row[2], s_lcol[2], s_arow[2];
    #pragma unroll
    for (int p = 0; p < 2; ++p) {
        int u = p * 256 + t;
        int row = u >> 2;
        int physu = u & 3;
        s_row[p]  = row;
        s_lcol[p] = ((physu ^ ((row >> 1) & 3)) << 4);
        int ar = tileM + row; if (ar > M - 1) ar = M - 1;
        s_arow[p] = ar;
    }

    #define REGOFF(buf_, op_, ks_) ((buf_) * 32768 + (op_) * 16384 + (ks_) * 8192)

    #define STAGE(tt_, op_, ks_, buf_)                                          \
    {   _Pragma("unroll")                                                       \
        for (int p = 0; p < 2; ++p) {                                           \
            int u = p * 256 + t;                                                \
            size_t gb;                                                          \
            if ((op_) == 0) gb = (size_t)s_arow[p] * 2048 + (tt_) * 128 + (ks_) * 64 + s_lcol[p]; \
            else            gb = (size_t)(tileN + s_row[p]) * 2048 + (tt_) * 128 + (ks_) * 64 + s_lcol[p]; \
            gload_lds16((((op_) == 0) ? Ab : Bb) + gb,                          \
                        LDS + REGOFF(buf_, op_, ks_) + u * 16);                 \
        } }

    auto rdA = [&](int buf, int ks, int mf) {
        int row = wr * 64 + mf * 16 + ml;
        int off = REGOFF(buf, 0, ks) + row * 64 + ((zz ^ ((row >> 1) & 3)) << 4);
        return *reinterpret_cast<const s16x8*>(LDS + off);
    };
    auto rdB = [&](int buf, int ks, int nf) {
        int row = wc * 64 + nf * 16 + ml;
        int off = REGOFF(buf, 1, ks) + row * 64 + ((zz ^ ((row >> 1) & 3)) << 4);
        return *reinterpret_cast<const s16x8*>(LDS + off);
    };

    f32x4 acc[4][4] = {};

    STAGE(0, 0, 0, 0); STAGE(0, 1, 0, 0); STAGE(0, 0, 1, 0); STAGE(0, 1, 1, 0);

    for (int tt = 0; tt < 16; ++tt) {
        const int buf = tt & 1, nbuf = buf ^ 1;
        const bool pre = (tt < 15);

        // ---- CP1: confirm Aks0,Bks0(tt) ----
        asm volatile("s_waitcnt vmcnt(4)" ::: "memory");
        __builtin_amdgcn_s_barrier();
        __builtin_amdgcn_sched_barrier(0);
        if (pre) STAGE(tt + 1, 0, 0, nbuf);

        s16x8 a[4];
        #pragma unroll
        for (int mf = 0; mf < 4; ++mf) a[mf] = rdA(buf, 0, mf);
        {
            s16x8 b0 = rdB(buf, 0, 0), b1 = rdB(buf, 0, 1);
            __builtin_amdgcn_s_setprio(1);
            #pragma unroll
            for (int mf = 0; mf < 4; ++mf) {
                acc[mf][0] = MFMA16(a[mf], b0, acc[mf][0]);
                acc[mf][1] = MFMA16(a[mf], b1, acc[mf][1]);
            }
            __builtin_amdgcn_s_setprio(0);
        }
        if (pre) STAGE(tt + 1, 1, 0, nbuf);
        {
            s16x8 b2 = rdB(buf, 0, 2), b3 = rdB(buf, 0, 3);
            __builtin_amdgcn_s_setprio(1);
            #pragma unroll
            for (int mf = 0; mf < 4; ++mf) {
                acc[mf][2] = MFMA16(a[mf], b2, acc[mf][2]);
                acc[mf][3] = MFMA16(a[mf], b3, acc[mf][3]);
            }
            __builtin_amdgcn_s_setprio(0);
        }

        // ---- CP2: confirm Aks1,Bks1(tt) ----
        if (pre) { asm volatile("s_waitcnt vmcnt(4)" ::: "memory"); }
        else     { asm volatile("s_waitcnt vmcnt(0)" ::: "memory"); }
        __builtin_amdgcn_s_barrier();
        __builtin_amdgcn_sched_barrier(0);
        if (pre) STAGE(tt + 1, 0, 1, nbuf);

        #pragma unroll
        for (int mf = 0; mf < 4; ++mf) a[mf] = rdA(buf, 1, mf);
        {
            s16x8 b0 = rdB(buf, 1, 0), b1 = rdB(buf, 1, 1);
            __builtin_amdgcn_s_setprio(1);
            #pragma unroll
            for (int mf = 0; mf < 4; ++mf) {
                acc[mf][0] = MFMA16(a[mf], b0, acc[mf][0]);
                acc[mf][1] = MFMA16(a[mf], b1, acc[mf][1]);
            }
            __builtin_amdgcn_s_setprio(0);
        }
        if (pre) STAGE(tt + 1, 1, 1, nbuf);
        {
            s16x8 b2 = rdB(buf, 1, 2), b3 = rdB(buf, 1, 3);
            __builtin_amdgcn_s_setprio(1);
            #pragma unroll
            for (int mf = 0; mf < 4; ++mf) {
                acc[mf][2] = MFMA16(a[mf], b2, acc[mf][2]);
                acc[mf][3] = MFMA16(a[mf], b3, acc[mf][3]);
            }
            __builtin_amdgcn_s_setprio(0);
        }
    }

    const int z2 = tileN >> 10;           // 0=Q, 1=K, 2=V
    short* Ob = (z2 == 0) ? Qb : (z2 == 1) ? Kb : Vb;
    const int cbase = (tileN & 1023) + wc * 64;

    #pragma unroll
    for (int mf = 0; mf < 4; ++mf) {
        #pragma unroll
        for (int j = 0; j < 4; ++j) {
            int row = tileM + wr * 64 + mf * 16 + zz * 4 + j;
            if (row < M) {
                int b = row / 577;
                int n = row - b * 577;
                #pragma unroll
                for (int nf = 0; nf < 4; ++nf) {
                    int cz = cbase + nf * 16 + ml;
                    int h = cz >> 6, dd = cz & 63;
                    Ob[(((size_t)(b * 16 + h)) * 577 + n) * 64 + dd] = f2bf(acc[mf][nf][j]);
                }
            }
        }
    }
    #undef STAGE
    #undef REGOFF
}

// ---------------------------------------------------------------------------
// V transpose: Vb [bh][n][d] -> Vt [bh][d][584]. 64x64 tiles via LDS.
// ---------------------------------------------------------------------------
__global__ __launch_bounds__(256) void vtrans(
    const short* __restrict__ Vb,
    short* __restrict__ Vt)
{
    __shared__ short lds[64 * 64];   // [d][n_local]
    const int t  = threadIdx.x;
    const int n0 = blockIdx.x * 64;
    const int bh = blockIdx.y;
    const size_t slab  = (size_t)bh * (577 * 64);
    const size_t vslab = (size_t)bh * (64 * 584);

    int r  = t >> 2;
    int d0 = (t & 3) * 16;
    int row = n0 + r; if (row > 576) row = 576;
    const short* src = Vb + slab + (size_t)row * 64 + d0;
    s16x8 v0 = *reinterpret_cast<const s16x8*>(src);
    s16x8 v1 = *reinterpret_cast<const s16x8*>(src + 8);
    #pragma unroll
    for (int j = 0; j < 8; ++j) {
        lds[(d0 + j) * 64 + r]     = v0[j];
        lds[(d0 + 8 + j) * 64 + r] = v1[j];
    }
    __syncthreads();
    #pragma unroll
    for (int p = 0; p < 2; ++p) {
        int u  = p * 256 + t;      // 0..511
        int dd = u >> 3, ns = u & 7;
        int n  = n0 + ns * 8;
        if (n < 584) {
            s16x8 vv = *reinterpret_cast<const s16x8*>(&lds[dd * 64 + ns * 8]);
            *reinterpret_cast<s16x8*>(Vt + vslab + (size_t)dd * 584 + n) = vv;
        }
    }
}

// ---------------------------------------------------------------------------
// Flash attention v6 (R14/R16, measured-best): occupancy-pinned (256,4),
// exp2-domain scores (Wq pre-scaled), repack folded into PV, counted
// vmcnt(4) double buffer.
// ---------------------------------------------------------------------------
__global__ __launch_bounds__(256, 4) void attn_fwd6(
    const short* __restrict__ Qb,
    const short* __restrict__ Kb,
    const short* __restrict__ Vt,
    float* __restrict__ out)
{
    constexpr int N = 577;

    __shared__ short K_lds[2][4096];
    __shared__ short V_lds[2][4096];

    const int t     = threadIdx.x;
    const int lane  = t & 63;
    const int w     = t >> 6;
    const int col_q = lane & 31;
    const int hi    = lane >> 5;
    const int hi8   = hi * 8;
    const int c7    = col_q & 7;

    int bd  = blockIdx.x;              // 0..5119
    int xx  = bd & 7;
    int r_  = bd >> 3;                 // 0..639
    int qt  = r_ % 5;
    int bh  = (r_ / 5) * 8 + xx;
    const int bB = bh >> 4, hH = bh & 15;
    const size_t slab  = (size_t)bh * (N * 64);
    const size_t vslab = (size_t)bh * (64 * 584);

    const int q0 = qt * 128 + w * 32;

    s16x8 qb[4];
    {
        int qr = q0 + col_q; if (qr > N - 1) qr = N - 1;
        const short* qrow = Qb + slab + (size_t)qr * 64 + hi8;
        #pragma unroll
        for (int ks = 0; ks < 4; ++ks)
            qb[ks] = *reinterpret_cast<const s16x8*>(qrow + ks * 16);
    }

    const int sr = t >> 3;          // staging row, 0..31 (+p*32)
    const int sp = t & 7;           // staging physical slot

    float m_run = -1e30f, l_run = 0.f;
    f32x16 o0 = {}, o1 = {};

    #pragma unroll
    for (int p = 0; p < 2; ++p) {
        int rr = p * 32 + sr;
        int sl = sp ^ (rr & 7);
        gload_lds16(Kb + slab + (size_t)rr * 64 + sl * 8, &K_lds[0][(rr * 8 + sp) * 8]);
        gload_lds16(Vt + vslab + (size_t)rr * 584 + sl * 8, &V_lds[0][(rr * 8 + sp) * 8]);
    }
    int cur = 0;

    for (int tile = 0; tile < 10; ++tile) {
        const int kv0 = tile * 64;
        __builtin_amdgcn_sched_barrier(0);
        __builtin_amdgcn_s_barrier();
        if (tile < 9) {
            #pragma unroll
            for (int p = 0; p < 2; ++p) {
                int rr = p * 32 + sr;
                int sl = sp ^ (rr & 7);
                gload_lds16(Kb + slab + (size_t)(kv0 + 64 + rr) * 64 + sl * 8,
                            &K_lds[cur ^ 1][(rr * 8 + sp) * 8]);
                gload_lds16(Vt + vslab + (size_t)rr * 584 + (kv0 + 64) + sl * 8,
                            &V_lds[cur ^ 1][(rr * 8 + sp) * 8]);
            }
            asm volatile("s_waitcnt vmcnt(4)" ::: "memory");
        } else {
            asm volatile("s_waitcnt vmcnt(0)" ::: "memory");
        }
        __builtin_amdgcn_sched_barrier(0);

        const short* KL = &K_lds[cur][0];
        const short* VL = &V_lds[cur][0];

        f32x16 s0 = {}, s1 = {};
        __builtin_amdgcn_s_setprio(1);
        #pragma unroll
        for (int ks = 0; ks < 4; ++ks) {
            s16x8 kf0 = *reinterpret_cast<const s16x8*>(
                KL + ((col_q * 8 + ((2*ks + hi) ^ c7)) * 8));
            s0 = MFMA32(kf0, qb[ks], s0);
        }
        #pragma unroll
        for (int ks = 0; ks < 4; ++ks) {
            s16x8 kf1 = *reinterpret_cast<const s16x8*>(
                KL + (((32 + col_q) * 8 + ((2*ks + hi) ^ c7)) * 8));
            s1 = MFMA32(kf1, qb[ks], s1);
        }
        __builtin_amdgcn_s_setprio(0);

        if (kv0 + 64 > N) {
            #pragma unroll
            for (int r = 0; r < 16; ++r) {
                int crow = (r & 3) + 8 * (r >> 2) + 4 * hi;
                if (kv0 + crow > N - 1) s0[r] = -1e30f;
                s1[r] = -1e30f;
            }
        }

        float pm = s0[0];
        #pragma unroll
        for (int r = 1; r < 15; r += 2) pm = fmaxf(fmaxf(pm, s0[r]), s0[r+1]);
        pm = fmaxf(pm, s0[15]);
        #pragma unroll
        for (int r = 0; r < 16; r += 2) pm = fmaxf(fmaxf(pm, s1[r]), s1[r+1]);
        float pmax2 = fmaxf(pm, __shfl_xor(pm, 32));

        bool need = (pmax2 - m_run) > 8.f;   // log2-domain threshold: P <= 2^8
        if (__ballot(need)) {
            float mn   = fmaxf(m_run, pmax2);
            float corr = exp2f(m_run - mn);
            m_run = mn;
            l_run *= corr;
            #pragma unroll
            for (int r = 0; r < 16; ++r) { o0[r] *= corr; o1[r] *= corr; }
        }
        float cmn = m_run;

        float psum = 0.f;
        #pragma unroll
        for (int r = 0; r < 16; ++r) { s0[r] = exp2f(s0[r] - cmn); psum += s0[r]; }
        #pragma unroll
        for (int r = 0; r < 16; ++r) { s1[r] = exp2f(s1[r] - cmn); psum += s1[r]; }
        l_run += psum + __shfl_xor(psum, 32);

        #define REPACK(S_, b_, dst_)                                              \
        {   u32x2 r1_ = __builtin_amdgcn_permlane32_swap(                         \
                cvtpk(S_[(b_)+0], S_[(b_)+1]), cvtpk(S_[(b_)+4], S_[(b_)+5]), false, false); \
            u32x2 r2_ = __builtin_amdgcn_permlane32_swap(                         \
                cvtpk(S_[(b_)+2], S_[(b_)+3]), cvtpk(S_[(b_)+6], S_[(b_)+7]), false, false); \
            dst_[0] = r1_[0]; dst_[2] = r1_[1]; dst_[1] = r2_[0]; dst_[3] = r2_[1]; }

        #define PVSTEP(ks_, S_, b_)                                               \
        {   u32x4 pwk_;                                                           \
            REPACK(S_, b_, pwk_);                                                 \
            s16x8 paf_ = __builtin_bit_cast(s16x8, pwk_);                         \
            s16x8 vf0_ = *reinterpret_cast<const s16x8*>(                         \
                VL + ((col_q * 8 + ((2*(ks_) + hi) ^ c7)) * 8));                  \
            o0 = MFMA32(vf0_, paf_, o0);                                          \
            s16x8 vf1_ = *reinterpret_cast<const s16x8*>(                         \
                VL + (((32 + col_q) * 8 + ((2*(ks_) + hi) ^ c7)) * 8));           \
            o1 = MFMA32(vf1_, paf_, o1);                                          \
        }

        __builtin_amdgcn_s_setprio(1);
        PVSTEP(0, s0, 0)
        PVSTEP(1, s0, 8)
        PVSTEP(2, s1, 0)
        PVSTEP(3, s1, 8)
        __builtin_amdgcn_s_setprio(0);
        #undef PVSTEP
        #undef REPACK
        cur ^= 1;
    }

    int q = q0 + col_q;
    if (q < N) {
        float inv = 1.0f / l_run;
        float* obase = out + ((size_t)bB * 577 + q) * 1024 + (size_t)hH * 64;
        #pragma unroll
        for (int gq = 0; gq < 4; ++gq) {
            float4 v0 = { o0[4*gq+0]*inv, o0[4*gq+1]*inv, o0[4*gq+2]*inv, o0[4*gq+3]*inv };
            *reinterpret_cast<float4*>(obase + 8*gq + 4*hi) = v0;
            float4 v1 = { o1[4*gq+0]*inv, o1[4*gq+1]*inv, o1[4*gq+2]*inv, o1[4*gq+3]*inv };
            *reinterpret_cast<float4*>(obase + 32 + 8*gq + 4*hi) = v1;
        }
    }
}

extern "C" void kernel_launch(void* const* d_in, const int* in_sizes, int n_in,
                              void* d_out, int out_size, void* d_ws, size_t ws_size,
                              hipStream_t stream) {
    const float* x  = (const float*)d_in[0];
    const float* Wq = (const float*)d_in[1];
    const float* Wk = (const float*)d_in[2];
    const float* Wv = (const float*)d_in[3];
    float* out = (float*)d_out;

    const size_t SZ   = (size_t)64 * 16 * 577 * 64 * 2;   // 75,628,544 B
    const size_t VTSZ = (size_t)1024 * 64 * 584 * 2;      // 76,546,048 B
    short* Qb = (short*)d_ws;
    short* Kb = (short*)((char*)d_ws + SZ);
    short* Vt = (short*)((char*)d_ws + 2 * SZ);
    short* Wb = (short*)((char*)d_ws + 2 * SZ + VTSZ);    // 6,291,456 B

    short* xb = (short*)d_out;                            // [0, SZ)
    short* Vb = (short*)((char*)d_out + SZ);              // [SZ, 2*SZ)

    convert_bf16<<<2048, 256, 0, stream>>>(x, Wq, Wk, Wv, xb, Wb);
    qkv_gemm8<<<dim3(289 * 24), 256, 0, stream>>>(xb, Wb, Qb, Kb, Vb);
    vtrans<<<dim3(10, 1024), 256, 0, stream>>>(Vb, Vt);
    attn_fwd6<<<5120, 256, 0, stream>>>(Qb, Kb, Vt, out);
}

// Round 21
// 480.962 us; speedup vs baseline: 1.1641x; 1.1641x over previous
//
#include <hip/hip_runtime.h>
#include <hip/hip_bf16.h>

// Problem: B=64, N=577, E=1024, H=16, D=64.
// out = softmax((xWq^T)(xWk^T)^T / 8) (xWv^T), head-split.
// Buffers:
//   d_out doubles as scratch: xb bf16 [0,75628544) + Vb bf16 [75628544,151257088).
//   ws: Qb [0,SZ) + Kb [SZ,2SZ) + Vt [2SZ,2SZ+VTSZ) + Wb (6.3MB).
//   Vt = [bh][d][584] (16B-aligned rows).
// Wq is pre-scaled by 0.125*log2(e) -> scores arrive in the exp2 domain.

typedef __attribute__((ext_vector_type(8))) short s16x8;
typedef __attribute__((ext_vector_type(4))) float f32x4;
typedef __attribute__((ext_vector_type(16))) float f32x16;
typedef __attribute__((ext_vector_type(4))) unsigned int u32x4;
typedef __attribute__((ext_vector_type(2))) unsigned int u32x2;

#define MFMA16(a, b, c) __builtin_amdgcn_mfma_f32_16x16x32_bf16((a), (b), (c), 0, 0, 0)
#define MFMA32(a, b, c) __builtin_amdgcn_mfma_f32_32x32x16_bf16((a), (b), (c), 0, 0, 0)

__device__ __forceinline__ short f2bf(float f) {
    unsigned u = __builtin_bit_cast(unsigned, f);
    u += 0x7FFFu + ((u >> 16) & 1u);   // round-to-nearest-even
    return (short)(u >> 16);
}

__device__ __forceinline__ unsigned cvtpk(float lo, float hi) {
    unsigned r;
    asm("v_cvt_pk_bf16_f32 %0, %1, %2" : "=v"(r) : "v"(lo), "v"(hi));
    return r;
}

__device__ __forceinline__ void gload_lds16(const void* g, void* l) {
    __builtin_amdgcn_global_load_lds(
        (const __attribute__((address_space(1))) unsigned int*)g,
        (__attribute__((address_space(3))) unsigned int*)l,
        16, 0, 0);
}

// ---------------------------------------------------------------------------
// Convert x -> xb (d_out lo) and Wq|Wk|Wv -> Wb (ws) as bf16.
// Wq (wsel==0) is scaled by 0.125*log2(e).
// ---------------------------------------------------------------------------
__global__ __launch_bounds__(256) void convert_bf16(
    const float* __restrict__ x,
    const float* __restrict__ Wq,
    const float* __restrict__ Wk,
    const float* __restrict__ Wv,
    short* __restrict__ xb,
    short* __restrict__ Wb)
{
    constexpr size_t NX = 37814272u / 8u;
    constexpr size_t NW = 1048576u / 8u;
    constexpr size_t NTOT = NX + 3u * NW;
    size_t stride = (size_t)gridDim.x * blockDim.x;
    for (size_t c = (size_t)blockIdx.x * blockDim.x + threadIdx.x; c < NTOT; c += stride) {
        const float* src;
        short* dst;
        size_t off;
        float scale = 1.0f;
        if (c < NX) { src = x; off = c * 8; dst = xb + off; }
        else {
            size_t cw = c - NX;
            int wsel = (int)(cw / NW);
            src = (wsel == 0) ? Wq : (wsel == 1) ? Wk : Wv;
            if (wsel == 0) scale = 0.18033688011112042f;
            off = (cw - (size_t)wsel * NW) * 8;
            dst = Wb + cw * 8;
        }
        float4 a0 = *reinterpret_cast<const float4*>(src + off);
        float4 a1 = *reinterpret_cast<const float4*>(src + off + 4);
        s16x8 v;
        v[0]=f2bf(a0.x*scale); v[1]=f2bf(a0.y*scale); v[2]=f2bf(a0.z*scale); v[3]=f2bf(a0.w*scale);
        v[4]=f2bf(a1.x*scale); v[5]=f2bf(a1.y*scale); v[6]=f2bf(a1.z*scale); v[7]=f2bf(a1.w*scale);
        *reinterpret_cast<s16x8*>(dst) = v;
    }
}

// ---------------------------------------------------------------------------
// QKV GEMM v3 (R10/R16 measured-best, 241 us / 963 TF): 256x256 tile, BK=64,
// 8 waves, 128 KiB LDS, counted-vmcnt 4-phase pipeline with per-quarter
// stages interleaved between phases (CP1/CP2 vmcnt(4)). 16x16x32 MFMA.
// ---------------------------------------------------------------------------
__global__ __launch_bounds__(512, 2) void qkv_gemm3(
    const short* __restrict__ xb,
    const short* __restrict__ Wb,
    short* __restrict__ Qb,
    short* __restrict__ Kb,
    short* __restrict__ Vb)
{
    constexpr int M = 36928;
    constexpr int NT = 12;                 // 3072/256
    constexpr int NWG = 145 * NT;          // 1740
    __shared__ char LDS[131072];

    const int t    = threadIdx.x;
    const int lane = t & 63;
    const int w    = t >> 6;
    const int wr   = w >> 2, wc = w & 3;
    const int ml   = lane & 15, zz = lane >> 4;

    int orig = blockIdx.x;
    int xcd  = orig & 7;
    constexpr int QO = NWG / 8, RO = NWG % 8;
    int id = (xcd < RO ? xcd * (QO + 1) : RO * (QO + 1) + (xcd - RO) * QO) + (orig >> 3);
    const int tileM = (id / NT) * 256;
    const int tileN = (id % NT) * 256;

    const char* Ab = (const char*)xb;
    const char* Bb = (const char*)Wb;

    int s_row[2], s_lcol[2], s_arow[2];
    #pragma unroll
    for (int p = 0; p < 2; ++p) {
        int u = p * 512 + t;
        int row = u >> 2;
        int physu = u & 3;
        s_row[p]  = row;
        s_lcol[p] = ((physu ^ ((row >> 1) & 3)) << 4);
        int ar = tileM + row; if (ar > M - 1) ar = M - 1;
        s_arow[p] = ar;
    }

    #define REGOFF(buf_, op_, ks_) ((buf_) * 65536 + (op_) * 32768 + (ks_) * 16384)

    #define STAGE(tt_, op_, ks_, buf_)                                          \
    {   _Pragma("unroll")                                                       \
        for (int p = 0; p < 2; ++p) {                                           \
            int u = p * 512 + t;                                                \
            size_t gb;                                                          \
            if ((op_) == 0) gb = (size_t)s_arow[p] * 2048 + (tt_) * 128 + (ks_) * 64 + s_lcol[p]; \
            else            gb = (size_t)(tileN + s_row[p]) * 2048 + (tt_) * 128 + (ks_) * 64 + s_lcol[p]; \
            gload_lds16((((op_) == 0) ? Ab : Bb) + gb,                          \
                        LDS + REGOFF(buf_, op_, ks_) + u * 16);                 \
        } }

    auto rdA = [&](int buf, int ks, int mf) {
        int row = wr * 128 + mf * 16 + ml;
        int off = REGOFF(buf, 0, ks) + row * 64 + ((zz ^ ((row >> 1) & 3)) << 4);
        return *reinterpret_cast<const s16x8*>(LDS + off);
    };
    auto rdB = [&](int buf, int ks, int nf) {
        int row = wc * 64 + nf * 16 + ml;
        int off = REGOFF(buf, 1, ks) + row * 64 + ((zz ^ ((row >> 1) & 3)) << 4);
        return *reinterpret_cast<const s16x8*>(LDS + off);
    };

    f32x4 acc[8][4] = {};

    STAGE(0, 0, 0, 0); STAGE(0, 1, 0, 0); STAGE(0, 0, 1, 0); STAGE(0, 1, 1, 0);

    for (int tt = 0; tt < 16; ++tt) {
        const int buf = tt & 1, nbuf = buf ^ 1;
        const bool pre = (tt < 15);

        asm volatile("s_waitcnt vmcnt(4)" ::: "memory");
        __builtin_amdgcn_s_barrier();
        __builtin_amdgcn_sched_barrier(0);
        if (pre) STAGE(tt + 1, 0, 0, nbuf);

        s16x8 a[8];
        #pragma unroll
        for (int mf = 0; mf < 8; ++mf) a[mf] = rdA(buf, 0, mf);
        {
            s16x8 b0 = rdB(buf, 0, 0), b1 = rdB(buf, 0, 1);
            __builtin_amdgcn_s_setprio(1);
            #pragma unroll
            for (int mf = 0; mf < 8; ++mf) {
                acc[mf][0] = MFMA16(a[mf], b0, acc[mf][0]);
                acc[mf][1] = MFMA16(a[mf], b1, acc[mf][1]);
            }
            __builtin_amdgcn_s_setprio(0);
        }
        if (pre) STAGE(tt + 1, 1, 0, nbuf);
        {
            s16x8 b2 = rdB(buf, 0, 2), b3 = rdB(buf, 0, 3);
            __builtin_amdgcn_s_setprio(1);
            #pragma unroll
            for (int mf = 0; mf < 8; ++mf) {
                acc[mf][2] = MFMA16(a[mf], b2, acc[mf][2]);
                acc[mf][3] = MFMA16(a[mf], b3, acc[mf][3]);
            }
            __builtin_amdgcn_s_setprio(0);
        }

        if (pre) { asm volatile("s_waitcnt vmcnt(4)" ::: "memory"); }
        else     { asm volatile("s_waitcnt vmcnt(0)" ::: "memory"); }
        __builtin_amdgcn_s_barrier();
        __builtin_amdgcn_sched_barrier(0);
        if (pre) STAGE(tt + 1, 0, 1, nbuf);

        #pragma unroll
        for (int mf = 0; mf < 8; ++mf) a[mf] = rdA(buf, 1, mf);
        {
            s16x8 b0 = rdB(buf, 1, 0), b1 = rdB(buf, 1, 1);
            __builtin_amdgcn_s_setprio(1);
            #pragma unroll
            for (int mf = 0; mf < 8; ++mf) {
                acc[mf][0] = MFMA16(a[mf], b0, acc[mf][0]);
                acc[mf][1] = MFMA16(a[mf], b1, acc[mf][1]);
            }
            __builtin_amdgcn_s_setprio(0);
        }
        if (pre) STAGE(tt + 1, 1, 1, nbuf);
        {
            s16x8 b2 = rdB(buf, 1, 2), b3 = rdB(buf, 1, 3);
            __builtin_amdgcn_s_setprio(1);
            #pragma unroll
            for (int mf = 0; mf < 8; ++mf) {
                acc[mf][2] = MFMA16(a[mf], b2, acc[mf][2]);
                acc[mf][3] = MFMA16(a[mf], b3, acc[mf][3]);
            }
            __builtin_amdgcn_s_setprio(0);
        }
    }

    const int z2 = tileN >> 10;
    short* Ob = (z2 == 0) ? Qb : (z2 == 1) ? Kb : Vb;
    const int cbase = (tileN & 1023) + wc * 64;

    #pragma unroll
    for (int mf = 0; mf < 8; ++mf) {
        #pragma unroll
        for (int j = 0; j < 4; ++j) {
            int row = tileM + wr * 128 + mf * 16 + zz * 4 + j;
            if (row < M) {
                int b = row / 577;
                int n = row - b * 577;
                #pragma unroll
                for (int nf = 0; nf < 4; ++nf) {
                    int cz = cbase + nf * 16 + ml;
                    int h = cz >> 6, dd = cz & 63;
                    Ob[(((size_t)(b * 16 + h)) * 577 + n) * 64 + dd] = f2bf(acc[mf][nf][j]);
                }
            }
        }
    }
    #undef STAGE
    #undef REGOFF
}

// ---------------------------------------------------------------------------
// V transpose: Vb [bh][n][d] -> Vt [bh][d][584]. 64x64 tiles via LDS.
// ---------------------------------------------------------------------------
__global__ __launch_bounds__(256) void vtrans(
    const short* __restrict__ Vb,
    short* __restrict__ Vt)
{
    __shared__ short lds[64 * 64];   // [d][n_local]
    const int t  = threadIdx.x;
    const int n0 = blockIdx.x * 64;
    const int bh = blockIdx.y;
    const size_t slab  = (size_t)bh * (577 * 64);
    const size_t vslab = (size_t)bh * (64 * 584);

    int r  = t >> 2;
    int d0 = (t & 3) * 16;
    int row = n0 + r; if (row > 576) row = 576;
    const short* src = Vb + slab + (size_t)row * 64 + d0;
    s16x8 v0 = *reinterpret_cast<const s16x8*>(src);
    s16x8 v1 = *reinterpret_cast<const s16x8*>(src + 8);
    #pragma unroll
    for (int j = 0; j < 8; ++j) {
        lds[(d0 + j) * 64 + r]     = v0[j];
        lds[(d0 + 8 + j) * 64 + r] = v1[j];
    }
    __syncthreads();
    #pragma unroll
    for (int p = 0; p < 2; ++p) {
        int u  = p * 256 + t;      // 0..511
        int dd = u >> 3, ns = u & 7;
        int n  = n0 + ns * 8;
        if (n < 584) {
            s16x8 vv = *reinterpret_cast<const s16x8*>(&lds[dd * 64 + ns * 8]);
            *reinterpret_cast<s16x8*>(Vt + vslab + (size_t)dd * 584 + n) = vv;
        }
    }
}

// ---------------------------------------------------------------------------
// Flash attention v6 (R14/R16, measured-best): occupancy-pinned (256,4),
// exp2-domain scores (Wq pre-scaled), repack folded into PV, counted
// vmcnt(4) double buffer.
// ---------------------------------------------------------------------------
__global__ __launch_bounds__(256, 4) void attn_fwd6(
    const short* __restrict__ Qb,
    const short* __restrict__ Kb,
    const short* __restrict__ Vt,
    float* __restrict__ out)
{
    constexpr int N = 577;

    __shared__ short K_lds[2][4096];
    __shared__ short V_lds[2][4096];

    const int t     = threadIdx.x;
    const int lane  = t & 63;
    const int w     = t >> 6;
    const int col_q = lane & 31;
    const int hi    = lane >> 5;
    const int hi8   = hi * 8;
    const int c7    = col_q & 7;

    int bd  = blockIdx.x;              // 0..5119
    int xx  = bd & 7;
    int r_  = bd >> 3;                 // 0..639
    int qt  = r_ % 5;
    int bh  = (r_ / 5) * 8 + xx;
    const int bB = bh >> 4, hH = bh & 15;
    const size_t slab  = (size_t)bh * (N * 64);
    const size_t vslab = (size_t)bh * (64 * 584);

    const int q0 = qt * 128 + w * 32;

    s16x8 qb[4];
    {
        int qr = q0 + col_q; if (qr > N - 1) qr = N - 1;
        const short* qrow = Qb + slab + (size_t)qr * 64 + hi8;
        #pragma unroll
        for (int ks = 0; ks < 4; ++ks)
            qb[ks] = *reinterpret_cast<const s16x8*>(qrow + ks * 16);
    }

    const int sr = t >> 3;          // staging row, 0..31 (+p*32)
    const int sp = t & 7;           // staging physical slot

    float m_run = -1e30f, l_run = 0.f;
    f32x16 o0 = {}, o1 = {};

    #pragma unroll
    for (int p = 0; p < 2; ++p) {
        int rr = p * 32 + sr;
        int sl = sp ^ (rr & 7);
        gload_lds16(Kb + slab + (size_t)rr * 64 + sl * 8, &K_lds[0][(rr * 8 + sp) * 8]);
        gload_lds16(Vt + vslab + (size_t)rr * 584 + sl * 8, &V_lds[0][(rr * 8 + sp) * 8]);
    }
    int cur = 0;

    for (int tile = 0; tile < 10; ++tile) {
        const int kv0 = tile * 64;
        __builtin_amdgcn_sched_barrier(0);
        __builtin_amdgcn_s_barrier();
        if (tile < 9) {
            #pragma unroll
            for (int p = 0; p < 2; ++p) {
                int rr = p * 32 + sr;
                int sl = sp ^ (rr & 7);
                gload_lds16(Kb + slab + (size_t)(kv0 + 64 + rr) * 64 + sl * 8,
                            &K_lds[cur ^ 1][(rr * 8 + sp) * 8]);
                gload_lds16(Vt + vslab + (size_t)rr * 584 + (kv0 + 64) + sl * 8,
                            &V_lds[cur ^ 1][(rr * 8 + sp) * 8]);
            }
            asm volatile("s_waitcnt vmcnt(4)" ::: "memory");
        } else {
            asm volatile("s_waitcnt vmcnt(0)" ::: "memory");
        }
        __builtin_amdgcn_sched_barrier(0);

        const short* KL = &K_lds[cur][0];
        const short* VL = &V_lds[cur][0];

        f32x16 s0 = {}, s1 = {};
        __builtin_amdgcn_s_setprio(1);
        #pragma unroll
        for (int ks = 0; ks < 4; ++ks) {
            s16x8 kf0 = *reinterpret_cast<const s16x8*>(
                KL + ((col_q * 8 + ((2*ks + hi) ^ c7)) * 8));
            s0 = MFMA32(kf0, qb[ks], s0);
        }
        #pragma unroll
        for (int ks = 0; ks < 4; ++ks) {
            s16x8 kf1 = *reinterpret_cast<const s16x8*>(
                KL + (((32 + col_q) * 8 + ((2*ks + hi) ^ c7)) * 8));
            s1 = MFMA32(kf1, qb[ks], s1);
        }
        __builtin_amdgcn_s_setprio(0);

        if (kv0 + 64 > N) {
            #pragma unroll
            for (int r = 0; r < 16; ++r) {
                int crow = (r & 3) + 8 * (r >> 2) + 4 * hi;
                if (kv0 + crow > N - 1) s0[r] = -1e30f;
                s1[r] = -1e30f;
            }
        }

        float pm = s0[0];
        #pragma unroll
        for (int r = 1; r < 15; r += 2) pm = fmaxf(fmaxf(pm, s0[r]), s0[r+1]);
        pm = fmaxf(pm, s0[15]);
        #pragma unroll
        for (int r = 0; r < 16; r += 2) pm = fmaxf(fmaxf(pm, s1[r]), s1[r+1]);
        float pmax2 = fmaxf(pm, __shfl_xor(pm, 32));

        bool need = (pmax2 - m_run) > 8.f;   // log2-domain threshold: P <= 2^8
        if (__ballot(need)) {
            float mn   = fmaxf(m_run, pmax2);
            float corr = exp2f(m_run - mn);
            m_run = mn;
            l_run *= corr;
            #pragma unroll
            for (int r = 0; r < 16; ++r) { o0[r] *= corr; o1[r] *= corr; }
        }
        float cmn = m_run;

        float psum = 0.f;
        #pragma unroll
        for (int r = 0; r < 16; ++r) { s0[r] = exp2f(s0[r] - cmn); psum += s0[r]; }
        #pragma unroll
        for (int r = 0; r < 16; ++r) { s1[r] = exp2f(s1[r] - cmn); psum += s1[r]; }
        l_run += psum + __shfl_xor(psum, 32);

        #define REPACK(S_, b_, dst_)                                              \
        {   u32x2 r1_ = __builtin_amdgcn_permlane32_swap(                         \
                cvtpk(S_[(b_)+0], S_[(b_)+1]), cvtpk(S_[(b_)+4], S_[(b_)+5]), false, false); \
            u32x2 r2_ = __builtin_amdgcn_permlane32_swap(                         \
                cvtpk(S_[(b_)+2], S_[(b_)+3]), cvtpk(S_[(b_)+6], S_[(b_)+7]), false, false); \
            dst_[0] = r1_[0]; dst_[2] = r1_[1]; dst_[1] = r2_[0]; dst_[3] = r2_[1]; }

        #define PVSTEP(ks_, S_, b_)                                               \
        {   u32x4 pwk_;                                                           \
            REPACK(S_, b_, pwk_);                                                 \
            s16x8 paf_ = __builtin_bit_cast(s16x8, pwk_);                         \
            s16x8 vf0_ = *reinterpret_cast<const s16x8*>(                         \
                VL + ((col_q * 8 + ((2*(ks_) + hi) ^ c7)) * 8));                  \
            o0 = MFMA32(vf0_, paf_, o0);                                          \
            s16x8 vf1_ = *reinterpret_cast<const s16x8*>(                         \
                VL + (((32 + col_q) * 8 + ((2*(ks_) + hi) ^ c7)) * 8));           \
            o1 = MFMA32(vf1_, paf_, o1);                                          \
        }

        __builtin_amdgcn_s_setprio(1);
        PVSTEP(0, s0, 0)
        PVSTEP(1, s0, 8)
        PVSTEP(2, s1, 0)
        PVSTEP(3, s1, 8)
        __builtin_amdgcn_s_setprio(0);
        #undef PVSTEP
        #undef REPACK
        cur ^= 1;
    }

    int q = q0 + col_q;
    if (q < N) {
        float inv = 1.0f / l_run;
        float* obase = out + ((size_t)bB * 577 + q) * 1024 + (size_t)hH * 64;
        #pragma unroll
        for (int gq = 0; gq < 4; ++gq) {
            float4 v0 = { o0[4*gq+0]*inv, o0[4*gq+1]*inv, o0[4*gq+2]*inv, o0[4*gq+3]*inv };
            *reinterpret_cast<float4*>(obase + 8*gq + 4*hi) = v0;
            float4 v1 = { o1[4*gq+0]*inv, o1[4*gq+1]*inv, o1[4*gq+2]*inv, o1[4*gq+3]*inv };
            *reinterpret_cast<float4*>(obase + 32 + 8*gq + 4*hi) = v1;
        }
    }
}

extern "C" void kernel_launch(void* const* d_in, const int* in_sizes, int n_in,
                              void* d_out, int out_size, void* d_ws, size_t ws_size,
                              hipStream_t stream) {
    const float* x  = (const float*)d_in[0];
    const float* Wq = (const float*)d_in[1];
    const float* Wk = (const float*)d_in[2];
    const float* Wv = (const float*)d_in[3];
    float* out = (float*)d_out;

    const size_t SZ   = (size_t)64 * 16 * 577 * 64 * 2;   // 75,628,544 B
    const size_t VTSZ = (size_t)1024 * 64 * 584 * 2;      // 76,546,048 B
    short* Qb = (short*)d_ws;
    short* Kb = (short*)((char*)d_ws + SZ);
    short* Vt = (short*)((char*)d_ws + 2 * SZ);
    short* Wb = (short*)((char*)d_ws + 2 * SZ + VTSZ);    // 6,291,456 B

    short* xb = (short*)d_out;                            // [0, SZ)
    short* Vb = (short*)((char*)d_out + SZ);              // [SZ, 2*SZ)

    convert_bf16<<<2048, 256, 0, stream>>>(x, Wq, Wk, Wv, xb, Wb);
    qkv_gemm3<<<dim3(145 * 12), 512, 0, stream>>>(xb, Wb, Qb, Kb, Vb);
    vtrans<<<dim3(10, 1024), 256, 0, stream>>>(Vb, Vt);
    attn_fwd6<<<5120, 256, 0, stream>>>(Qb, Kb, Vt, out);
}